// Round 7
// baseline (167.111 us; speedup 1.0000x reference)
//
#include <hip/hip_runtime.h>

typedef __attribute__((ext_vector_type(8))) short short8;
typedef __attribute__((ext_vector_type(16))) float f32x16;

// ws layout:
//   Ft2  [z=512][yy=66][xx=66][8] bf16 halo-padded features, z = c*8 + b   (35.68 MB)
//   wt2  [slab=72][n=128][64] bf16 swizzled B slabs (LDS image)            (1.18 MB)
#define FT2_SHORTS (512u * 4356u * 8u)     // 17,842,176
#define PLANE16    4356                     // 66*66 (16B units per z-plane)

typedef __attribute__((address_space(3))) unsigned int lds_u32_t;
typedef __attribute__((address_space(1))) const unsigned int g_u32_t;

__device__ __forceinline__ unsigned short f2bf(float x) {
    union { float f; unsigned u; } v; v.f = x;
    unsigned r = v.u + 0x7FFFu + ((v.u >> 16) & 1u);   // RNE bf16
    return (unsigned short)(r >> 16);
}

// 7 features of p: silu, 6 cubic B-spline bases (uniform knots -3 + j*2/3), + zero pad
__device__ __forceinline__ void feat8(float p, unsigned short* uf) {
    float e   = __expf(-p);
    float sig = 1.f / (1.f + e);
    uf[0] = f2bf(p * sig);
    float u  = p * 1.5f + 4.5f;
    float fj = floorf(u);
    int   j0 = (int)fj;
    float t  = u - fj;
    bool  inr = (u >= 0.f) && (u < 9.f);
    float t2 = t * t, t3 = t2 * t;
    const float c16 = 1.f / 6.f;
    float r0 = t3 * c16;
    float r1 = (-3.f * t3 + 3.f * t2 + 3.f * t + 1.f) * c16;
    float r2 = (3.f * t3 - 6.f * t2 + 4.f) * c16;
    float s1 = 1.f - t;
    float r3 = s1 * s1 * s1 * c16;
#pragma unroll
    for (int g = 0; g < 6; ++g) {
        int r = j0 - g;
        float v = (r == 0) ? r0 : ((r == 1) ? r1 : ((r == 2) ? r2 : ((r == 3) ? r3 : 0.f)));
        uf[1 + g] = f2bf(inr ? v : 0.f);
    }
    uf[7] = 0;
}

// ---- Fused prep: per block (512): 144 B-chunks + 1 halo plane + 1 feature line ----
// All three write disjoint ws regions; no ordering needed between them.
__global__ __launch_bounds__(256)
void prep_all(const float* __restrict__ x,
              const float* __restrict__ bw, const float* __restrict__ sw,
              unsigned short* __restrict__ ft, unsigned short* __restrict__ wt) {
    const int blk = blockIdx.x;          // 0..511
    const int tid = threadIdx.x;

    // (1) B prep: item idx = blk*144 + tid, tid < 144  (512*144 = 73728 = 128*576)
    if (tid < 144) {
        int idx = blk * 144 + tid;
        int o = idx / 576;
        int i = idx - o * 576;
        int slab = i >> 3, e = i & 7;
        int ch = e ^ (o & 7);            // 8-chunk XOR swizzle
        union { unsigned short u[8]; uint4 v; } pk;
        pk.u[0] = f2bf(bw[o * 576 + i]);
        const float* s = sw + (size_t)(o * 576 + i) * 6;
#pragma unroll
        for (int f = 0; f < 6; ++f) pk.u[1 + f] = f2bf(s[f]);
        pk.u[7] = 0;
        *(uint4*)(wt + ((size_t)slab * 8192 + o * 64 + ch * 8)) = pk.v;
    }

    // (2) halo plane z = blk: feat8(0) into the 260 border cells
    {
        short8 pad = { 0, 0, (short)0x3CAB, (short)0x3EF5,
                       (short)0x3EF5, (short)0x3CAB, 0, 0 };
        for (int t = tid; t < 260; t += 256) {
            int yy, xx;
            if (t < 66)       { yy = 0;       xx = t; }
            else if (t < 132) { yy = 65;      xx = t - 66; }
            else if (t < 196) { yy = t - 131; xx = 0; }
            else              { yy = t - 195; xx = 65; }
            ((short8*)ft)[blk * PLANE16 + yy * 66 + xx] = pad;
        }
    }

    // (3) features for line = blk (b = blk>>6, y = blk&63)
    __shared__ float Xl[64 * 65];
    const int b = blk >> 6, y = blk & 63;
    const float* xl = x + (size_t)blk * 4096;
    for (int f4 = tid; f4 < 1024; f4 += 256) {
        float4 v = ((const float4*)xl)[f4];
        int xx = f4 >> 4, c4 = (f4 & 15) << 2;
        float* d = &Xl[xx * 65 + c4];
        d[0] = v.x; d[1] = v.y; d[2] = v.z; d[3] = v.w;
    }
    __syncthreads();
    const int xx = tid & 63;
    const int cw = tid >> 6;
#pragma unroll 4
    for (int p = 0; p < 16; ++p) {
        int c = cw + (p << 2);
        float pv = Xl[xx * 65 + c];
        union { unsigned short u[8]; uint4 v; } pk;
        feat8(pv, pk.u);
        size_t o16 = (size_t)(c * 8 + b) * PLANE16 + (y + 1) * 66 + (xx + 1);
        *(uint4*)(ft + (o16 << 3)) = pk.v;
    }
}

// ---- Main GEMM: grid 512, block 256 (4 waves = 4 n-groups), tile 64m x 128n ----
// wave = 64m x 32n: per k-step 2 A-chunks (global, halo-padded) + 1 B-frag (LDS) + 2 MFMA
#define STAGE(itn)                                                               \
    {                                                                            \
        const unsigned short* ssrc = wt + (size_t)(itn) * 8192 + stoff;          \
        unsigned short* sdst = &Bs[((itn) & 1) ? 8192 : 0] + stoff;              \
        _Pragma("unroll")                                                        \
        for (int j = 0; j < 4; ++j)                                              \
            __builtin_amdgcn_global_load_lds((g_u32_t*)(ssrc + j * 2048),        \
                                             (lds_u32_t*)(sdst + j * 2048), 16, 0, 0); \
    }

#define ALOAD(itn, ADST)                                                         \
    _Pragma("unroll")                                                            \
    for (int s_ = 0; s_ < 4; ++s_) {                                             \
        int i_  = (itn) * 8 + s_ * 2 + h;                                        \
        int c_  = (i_ * 7282) >> 16;                                             \
        int i9_ = i_ - c_ * 9;                                                   \
        int kh_ = (i9_ * 11) >> 5;                                               \
        int kw_ = i9_ - kh_ * 3;                                                 \
        int t16 = c_ * (8 * PLANE16) + kh_ * 66 + kw_ + abase;                   \
        ADST[2 * s_]     = fptr[t16];                                            \
        ADST[2 * s_ + 1] = fptr[t16 + 32];                                       \
    }

#define KSTEP(s_, ACUR)                                                          \
    {                                                                            \
        short8 bf = *(const short8*)(bsrd + roff + ((((s_) * 2 + h) ^ swb) << 4)); \
        acc0 = __builtin_amdgcn_mfma_f32_32x32x16_bf16(ACUR[2*(s_)],   bf, acc0, 0, 0, 0); \
        acc1 = __builtin_amdgcn_mfma_f32_32x32x16_bf16(ACUR[2*(s_)+1], bf, acc1, 0, 0, 0); \
    }

__global__ __launch_bounds__(256, 2)
void convkan_gemm(const unsigned short* __restrict__ ft,
                  const unsigned short* __restrict__ wt,
                  const float* __restrict__ bias,
                  float* __restrict__ out) {
    __shared__ unsigned short Bs[2 * 8192];     // 2 x 16 KB B slabs (K=64 each)

    const int tid  = threadIdx.x;
    const int blk  = blockIdx.x;                 // 512 blocks = 1 image line each
    const int lane = tid & 63;
    const int wave = tid >> 6;                   // 0..3 = n-group of 32
    const int l32  = lane & 31;
    const int h    = lane >> 5;                  // k-half

    const int b = blk >> 6;
    const int y = blk & 63;
    // addr16 = c*8*PLANE16 + b*PLANE16 + (y+kh)*66 + (ms*32 + l32 + kw)  (halo folds -1)
    const int abase = b * PLANE16 + y * 66 + l32;
    const short8* fptr = (const short8*)ft;

    const int stoff = wave * 512 + lane * 8;     // staging offset (shorts)

    const int roff = (wave * 32 + l32) * 128;    // B row byte offset
    const int swb  = l32 & 7;

    f32x16 acc0, acc1;
#pragma unroll
    for (int e = 0; e < 16; ++e) { acc0[e] = 0.f; acc1[e] = 0.f; }

    short8 aA[8], aB[8];
    STAGE(0);
    ALOAD(0, aA);

    for (int it = 0; it < 72; it += 2) {
        __syncthreads();                          // slab(it) resident in buf0
        STAGE(it + 1);
        ALOAD(it + 1, aB);
        {
            const char* bsrd = (const char*)Bs;   // buf0
            KSTEP(0, aA) KSTEP(1, aA) KSTEP(2, aA) KSTEP(3, aA)
        }
        __syncthreads();                          // slab(it+1) resident in buf1
        if (it + 2 < 72) {
            STAGE(it + 2);
            ALOAD(it + 2, aA);
        }
        {
            const char* bsrd = (const char*)Bs + 16384;   // buf1
            KSTEP(0, aB) KSTEP(1, aB) KSTEP(2, aB) KSTEP(3, aB)
        }
    }

    // epilogue: C/D row = (r&3) + 8*(r>>2) + 4*h (+ ms*32), col = l32 (+ wave*32)
    const float bv = bias[wave * 32 + l32];
    const int mrow0 = blk * 64 + h * 4;
    float* o0 = out + (size_t)mrow0 * 128 + wave * 32 + l32;
#pragma unroll
    for (int r = 0; r < 16; ++r) {
        int row = (r & 3) + ((r >> 2) << 3);
        o0[(size_t)row * 128]        = acc0[r] + bv;
        o0[(size_t)(row + 32) * 128] = acc1[r] + bv;
    }
}

extern "C" void kernel_launch(void* const* d_in, const int* in_sizes, int n_in,
                              void* d_out, int out_size, void* d_ws, size_t ws_size,
                              hipStream_t stream) {
    (void)in_sizes; (void)n_in; (void)out_size; (void)ws_size;
    const float* x        = (const float*)d_in[0];
    const float* base_w   = (const float*)d_in[1];
    const float* spline_w = (const float*)d_in[2];
    const float* bias     = (const float*)d_in[3];
    float* out = (float*)d_out;

    unsigned short* ft = (unsigned short*)d_ws;      // 35.68 MB halo features
    unsigned short* wt = ft + FT2_SHORTS;            // 1.18 MB tiled B

    hipLaunchKernelGGL(prep_all, dim3(512), dim3(256), 0, stream,
                       x, base_w, spline_w, ft, wt);
    hipLaunchKernelGGL(convkan_gemm, dim3(512), dim3(256), 0, stream,
                       ft, wt, bias, out);
}

// Round 8
// 148.885 us; speedup vs baseline: 1.1224x; 1.1224x over previous
//
#include <hip/hip_runtime.h>

typedef __attribute__((ext_vector_type(8))) short short8;
typedef __attribute__((ext_vector_type(16))) float f32x16;

// ws layout:
//   Ft2  [z=512][yy=66][xx=66][8] bf16 halo-padded features, z = c*8 + b   (35.68 MB)
//   wt2  [slab=72][e=8][n=128][8] bf16 B slabs, e = i&7 (chunk-major!)     (1.18 MB)
#define FT2_SHORTS (512u * 4356u * 8u)
#define PLANE16    4356

typedef __attribute__((address_space(3))) unsigned int lds_u32_t;
typedef __attribute__((address_space(1))) const unsigned int g_u32_t;

__device__ __forceinline__ unsigned short f2bf(float x) {
    union { float f; unsigned u; } v; v.f = x;
    unsigned r = v.u + 0x7FFFu + ((v.u >> 16) & 1u);   // RNE bf16
    return (unsigned short)(r >> 16);
}

__device__ __forceinline__ void feat8(float p, unsigned short* uf) {
    float e   = __expf(-p);
    float sig = 1.f / (1.f + e);
    uf[0] = f2bf(p * sig);
    float u  = p * 1.5f + 4.5f;
    float fj = floorf(u);
    int   j0 = (int)fj;
    float t  = u - fj;
    bool  inr = (u >= 0.f) && (u < 9.f);
    float t2 = t * t, t3 = t2 * t;
    const float c16 = 1.f / 6.f;
    float r0 = t3 * c16;
    float r1 = (-3.f * t3 + 3.f * t2 + 3.f * t + 1.f) * c16;
    float r2 = (3.f * t3 - 6.f * t2 + 4.f) * c16;
    float s1 = 1.f - t;
    float r3 = s1 * s1 * s1 * c16;
#pragma unroll
    for (int g = 0; g < 6; ++g) {
        int r = j0 - g;
        float v = (r == 0) ? r0 : ((r == 1) ? r1 : ((r == 2) ? r2 : ((r == 3) ? r3 : 0.f)));
        uf[1 + g] = f2bf(inr ? v : 0.f);
    }
    uf[7] = 0;
}

// ---- Fused prep: per block (512): 144 B-chunks + 1 halo plane + 1 feature line ----
__global__ __launch_bounds__(256)
void prep_all(const float* __restrict__ x,
              const float* __restrict__ bw, const float* __restrict__ sw,
              unsigned short* __restrict__ ft, unsigned short* __restrict__ wt) {
    const int blk = blockIdx.x;          // 0..511
    const int tid = threadIdx.x;

    // (1) B prep into chunk-major layout: wt[slab][i&7][n][8]
    if (tid < 144) {
        int idx = blk * 144 + tid;
        int o = idx / 576;
        int i = idx - o * 576;
        int slab = i >> 3, e = i & 7;
        union { unsigned short u[8]; uint4 v; } pk;
        pk.u[0] = f2bf(bw[o * 576 + i]);
        const float* s = sw + (size_t)(o * 576 + i) * 6;
#pragma unroll
        for (int f = 0; f < 6; ++f) pk.u[1 + f] = f2bf(s[f]);
        pk.u[7] = 0;
        *(uint4*)(wt + ((size_t)slab * 8192 + e * 1024 + o * 8)) = pk.v;
    }

    // (2) halo plane z = blk: feat8(0) into the 260 border cells
    {
        short8 pad = { 0, 0, (short)0x3CAB, (short)0x3EF5,
                       (short)0x3EF5, (short)0x3CAB, 0, 0 };
        for (int t = tid; t < 260; t += 256) {
            int yy, xx;
            if (t < 66)       { yy = 0;       xx = t; }
            else if (t < 132) { yy = 65;      xx = t - 66; }
            else if (t < 196) { yy = t - 131; xx = 0; }
            else              { yy = t - 195; xx = 65; }
            ((short8*)ft)[blk * PLANE16 + yy * 66 + xx] = pad;
        }
    }

    // (3) features for line = blk (b = blk>>6, y = blk&63)
    __shared__ float Xl[64 * 65];
    const int b = blk >> 6, y = blk & 63;
    const float* xl = x + (size_t)blk * 4096;
    for (int f4 = tid; f4 < 1024; f4 += 256) {
        float4 v = ((const float4*)xl)[f4];
        int xx = f4 >> 4, c4 = (f4 & 15) << 2;
        float* d = &Xl[xx * 65 + c4];
        d[0] = v.x; d[1] = v.y; d[2] = v.z; d[3] = v.w;
    }
    __syncthreads();
    const int xx = tid & 63;
    const int cw = tid >> 6;
#pragma unroll 4
    for (int p = 0; p < 16; ++p) {
        int c = cw + (p << 2);
        float pv = Xl[xx * 65 + c];
        union { unsigned short u[8]; uint4 v; } pk;
        feat8(pv, pk.u);
        size_t o16 = (size_t)(c * 8 + b) * PLANE16 + (y + 1) * 66 + (xx + 1);
        *(uint4*)(ft + (o16 << 3)) = pk.v;
    }
}

// ---- Main GEMM: K-split 2, grid 512 (mb 0..255 x kk 0..1), block 256 ----
// tile 128m(2 lines) x 128n, wave = 64m x 64n (g = line, nh = n-half)
// LDS buf (32 KB): [B: 8 chunk-slices x 128n x 16B = 16 KB][A: 16 idx x 64px x 16B = 16 KB]
// double-buffered = 64 KB; A and B both DMA-staged; one barrier per K=64 slab.
#define STAGE_AB(sl)                                                                  \
    {                                                                                 \
        unsigned short* bufb = Bufs + (((sl) & 1) << 14);                             \
        const unsigned short* bsrc = wt + (size_t)(slab0 + (sl)) * 8192 + bsoff;      \
        unsigned short* bdst = bufb + bsoff;                                          \
        _Pragma("unroll")                                                             \
        for (int t = 0; t < 4; ++t)                                                   \
            __builtin_amdgcn_global_load_lds((g_u32_t*)(bsrc + t * 512),              \
                                             (lds_u32_t*)(bdst + t * 512), 16, 0, 0); \
        _Pragma("unroll")                                                             \
        for (int t = 0; t < 4; ++t) {                                                 \
            int idx = wave * 4 + t;                                                   \
            int ia  = (slab0 + (sl)) * 8 + (idx >> 1);                                \
            int g2  = idx & 1;                                                        \
            int c_  = (ia * 7282) >> 16;                                              \
            int i9_ = ia - c_ * 9;                                                    \
            int kh_ = (i9_ * 11) >> 5;                                                \
            int kw_ = i9_ - kh_ * 3;                                                  \
            const unsigned short* asrc = ft +                                         \
                (((size_t)(c_ * 8 + b) * PLANE16 + (y0 + g2 + kh_) * 66 + kw_) << 3)  \
                + lane * 8;                                                           \
            unsigned short* adst = bufb + 8192 + idx * 512 + lane * 8;                \
            __builtin_amdgcn_global_load_lds((g_u32_t*)asrc, (lds_u32_t*)adst,        \
                                             16, 0, 0);                               \
        }                                                                             \
    }

#define KSTEP(s_)                                                                     \
    {                                                                                 \
        int iloc = 2 * (s_) + h;                                                      \
        const unsigned short* Ab = bufr + 8192 + (iloc * 2 + g) * 512;                \
        const unsigned short* Bb = bufr + iloc * 1024;                                \
        short8 a0 = *(const short8*)(Ab + l32 * 8);                                   \
        short8 a1 = *(const short8*)(Ab + (32 + l32) * 8);                            \
        short8 b0 = *(const short8*)(Bb + (nh * 64 + l32) * 8);                       \
        short8 b1 = *(const short8*)(Bb + (nh * 64 + 32 + l32) * 8);                  \
        acc00 = __builtin_amdgcn_mfma_f32_32x32x16_bf16(a0, b0, acc00, 0, 0, 0);      \
        acc01 = __builtin_amdgcn_mfma_f32_32x32x16_bf16(a0, b1, acc01, 0, 0, 0);      \
        acc10 = __builtin_amdgcn_mfma_f32_32x32x16_bf16(a1, b0, acc10, 0, 0, 0);      \
        acc11 = __builtin_amdgcn_mfma_f32_32x32x16_bf16(a1, b1, acc11, 0, 0, 0);      \
    }

__global__ __launch_bounds__(256, 2)
void convkan_gemm(const unsigned short* __restrict__ ft,
                  const unsigned short* __restrict__ wt,
                  const float* __restrict__ bias,
                  float* __restrict__ out) {
    extern __shared__ unsigned short Bufs[];     // 2 x 16384 shorts = 64 KB

    const int tid  = threadIdx.x;
    const int blk  = blockIdx.x;                 // 512 blocks
    const int kk   = blk & 1;                    // K-half
    const int mb   = blk >> 1;                   // 0..255 (2 lines each)
    const int lane = tid & 63;
    const int wave = tid >> 6;
    const int g    = wave >> 1;                  // line within tile
    const int nh   = wave & 1;                   // n-half (64)
    const int l32  = lane & 31;
    const int h    = lane >> 5;                  // k-half

    const int b  = mb >> 5;
    const int y0 = (mb & 31) << 1;
    const int slab0 = kk * 36;

    const int bsoff = wave * 2048 + lane * 8;    // B staging: wave covers 4 KB

    f32x16 acc00, acc01, acc10, acc11;
#pragma unroll
    for (int e = 0; e < 16; ++e) { acc00[e] = 0.f; acc01[e] = 0.f; acc10[e] = 0.f; acc11[e] = 0.f; }

    STAGE_AB(0);
    __syncthreads();                             // cold drain, once

    for (int it = 0; it < 36; ++it) {
        if (it + 1 < 36) STAGE_AB(it + 1);       // lands during this phase's compute
        const unsigned short* bufr = Bufs + ((it & 1) << 14);
        KSTEP(0) KSTEP(1) KSTEP(2) KSTEP(3)
        __syncthreads();                         // drains STAGE(it+1) (one phase old)
    }

    // epilogue: C/D row = (r&3)+8*(r>>2)+4*h, col = l32; accumulate via f32 atomics
    const float bv0 = kk ? 0.f : bias[nh * 64 + l32];
    const float bv1 = kk ? 0.f : bias[nh * 64 + 32 + l32];
    const int prow = (mb * 2 + g) * 64;          // output pixel-row base for this wave
    const int ncol = nh * 64 + l32;
#pragma unroll
    for (int r = 0; r < 16; ++r) {
        int mrow = (r & 3) + ((r >> 2) << 3) + 4 * h;
        float* p0 = out + (size_t)(prow + mrow) * 128 + ncol;
        float* p1 = out + (size_t)(prow + 32 + mrow) * 128 + ncol;
        atomicAdd(p0,      acc00[r] + bv0);
        atomicAdd(p0 + 32, acc01[r] + bv1);
        atomicAdd(p1,      acc10[r] + bv0);
        atomicAdd(p1 + 32, acc11[r] + bv1);
    }
}

extern "C" void kernel_launch(void* const* d_in, const int* in_sizes, int n_in,
                              void* d_out, int out_size, void* d_ws, size_t ws_size,
                              hipStream_t stream) {
    (void)in_sizes; (void)n_in; (void)ws_size;
    const float* x        = (const float*)d_in[0];
    const float* base_w   = (const float*)d_in[1];
    const float* spline_w = (const float*)d_in[2];
    const float* bias     = (const float*)d_in[3];
    float* out = (float*)d_out;

    unsigned short* ft = (unsigned short*)d_ws;      // 35.68 MB halo features
    unsigned short* wt = ft + FT2_SHORTS;            // 1.18 MB tiled B

    hipMemsetAsync(out, 0, (size_t)out_size * sizeof(float), stream);
    hipLaunchKernelGGL(prep_all, dim3(512), dim3(256), 0, stream,
                       x, base_w, spline_w, ft, wt);

    const int shmem = 2 * 16384 * 2;                 // 64 KB
    (void)hipFuncSetAttribute((const void*)convkan_gemm,
                              hipFuncAttributeMaxDynamicSharedMemorySize, shmem);
    hipLaunchKernelGGL(convkan_gemm, dim3(512), dim3(256), shmem, stream,
                       ft, wt, bias, out);
}